// Round 1
// baseline (3190.899 us; speedup 1.0000x reference)
//
#include <hip/hip_runtime.h>

// GCN with DIM=1: all layer "matmuls" are scalar ops. Structure:
//   h0 = relu(scatter_sum(x@W0n over edges) + b0 + x@W0s)
//   hk = relu(Wkn*scatter_sum(h) + bk + Wks*h)   (3x)
//   hg = segment_sum(h, graph_ids)  -> tiny MLP head -> log_softmax

static constexpr int NGRAPHS = 256;

__global__ void node_init(const float4* __restrict__ x,
                          const float* __restrict__ W0n,
                          const float* __restrict__ W0s,
                          float* __restrict__ xw0,
                          float* __restrict__ s0,
                          int n_nodes) {
    int n = blockIdx.x * blockDim.x + threadIdx.x;
    if (n >= n_nodes) return;
    float4 a = x[2 * n];
    float4 b = x[2 * n + 1];
    float xn = a.x * W0n[0] + a.y * W0n[1] + a.z * W0n[2] + a.w * W0n[3] +
               b.x * W0n[4] + b.y * W0n[5] + b.z * W0n[6] + b.w * W0n[7];
    float xs = a.x * W0s[0] + a.y * W0s[1] + a.z * W0s[2] + a.w * W0s[3] +
               b.x * W0s[4] + b.y * W0s[5] + b.z * W0s[6] + b.w * W0s[7];
    xw0[n] = xn;
    s0[n] = xs;
}

// Scatter-add val[src] into agg[dst], 4 edges per thread via int4 index loads.
__global__ void edge_scatter(const int4* __restrict__ src4,
                             const int4* __restrict__ dst4,
                             const float* __restrict__ val,
                             float* __restrict__ agg,
                             int nquads) {
    int t = blockIdx.x * blockDim.x + threadIdx.x;
    if (t >= nquads) return;
    int4 s = src4[t];
    int4 d = dst4[t];
    float v0 = val[s.x];
    float v1 = val[s.y];
    float v2 = val[s.z];
    float v3 = val[s.w];
    atomicAdd(&agg[d.x], v0);
    atomicAdd(&agg[d.y], v1);
    atomicAdd(&agg[d.z], v2);
    atomicAdd(&agg[d.w], v3);
}

// Layer 0 node update: h = relu(agg + b0 + s0); reset agg for next layer.
__global__ void node_l0(float* __restrict__ agg,
                        const float* __restrict__ s0,
                        const float* __restrict__ b0,
                        float* __restrict__ h,
                        int n_nodes) {
    int n = blockIdx.x * blockDim.x + threadIdx.x;
    if (n >= n_nodes) return;
    float v = agg[n] + b0[0] + s0[n];
    h[n] = fmaxf(v, 0.0f);
    agg[n] = 0.0f;
}

// Layers 1..2 node update: h = relu(wn*agg + b + ws*h); reset agg.
__global__ void node_lk(float* __restrict__ agg,
                        float* __restrict__ h,
                        const float* __restrict__ Wkn,
                        const float* __restrict__ bk,
                        const float* __restrict__ Wks,
                        int li,
                        int n_nodes) {
    int n = blockIdx.x * blockDim.x + threadIdx.x;
    if (n >= n_nodes) return;
    float wn = Wkn[li];
    float b  = bk[li];
    float ws = Wks[li];
    float v = wn * agg[n] + b + ws * h[n];
    h[n] = fmaxf(v, 0.0f);
    agg[n] = 0.0f;
}

// Layer 3 node update fused with graph readout. graph_ids is sorted, so a
// 64-lane wave is almost always graph-uniform -> butterfly reduce + 1 atomic.
__global__ void node_l3_readout(const float* __restrict__ agg,
                                const float* __restrict__ h,
                                const int* __restrict__ graph_ids,
                                const float* __restrict__ Wkn,
                                const float* __restrict__ bk,
                                const float* __restrict__ Wks,
                                float* __restrict__ hg,
                                int n_nodes) {
    int n = blockIdx.x * blockDim.x + threadIdx.x;
    float val = 0.0f;
    int g = -1;
    if (n < n_nodes) {
        float wn = Wkn[2];
        float b  = bk[2];
        float ws = Wks[2];
        float v = wn * agg[n] + b + ws * h[n];
        val = fmaxf(v, 0.0f);
        g = graph_ids[n];
    }
    int g0 = __shfl(g, 0);
    unsigned long long same = __ballot(g == g0);
    if (same == ~0ULL) {
        // wave-uniform graph id: reduce across 64 lanes
        for (int o = 32; o > 0; o >>= 1) val += __shfl_down(val, o);
        if ((threadIdx.x & 63) == 0 && g >= 0) atomicAdd(&hg[g], val);
    } else if (g >= 0) {
        atomicAdd(&hg[g], val);
    }
}

// 256-graph MLP head + log_softmax. One block.
__global__ void head(const float* __restrict__ hg,
                     const float* __restrict__ fc1_w,
                     const float* __restrict__ fc1_b,
                     const float* __restrict__ out_w,
                     const float* __restrict__ out_b,
                     float* __restrict__ out) {
    int gph = threadIdx.x;
    if (gph >= NGRAPHS) return;
    float hv = hg[gph];
    float o0 = out_b[0], o1 = out_b[1], o2 = out_b[2], o3 = out_b[3];
#pragma unroll
    for (int j = 0; j < 8; ++j) {
        float z = (hv * fc1_w[j] + fc1_b[j]) * 1000.0f;
        float sg = 1.0f / (1.0f + expf(-z));
        o0 += sg * out_w[j * 4 + 0];
        o1 += sg * out_w[j * 4 + 1];
        o2 += sg * out_w[j * 4 + 2];
        o3 += sg * out_w[j * 4 + 3];
    }
    o0 = fmaxf(o0, 0.0f);
    o1 = fmaxf(o1, 0.0f);
    o2 = fmaxf(o2, 0.0f);
    o3 = fmaxf(o3, 0.0f);
    float m = fmaxf(fmaxf(o0, o1), fmaxf(o2, o3));
    float s = expf(o0 - m) + expf(o1 - m) + expf(o2 - m) + expf(o3 - m);
    float l = logf(s);
    out[gph * 4 + 0] = o0 - m - l;
    out[gph * 4 + 1] = o1 - m - l;
    out[gph * 4 + 2] = o2 - m - l;
    out[gph * 4 + 3] = o3 - m - l;
}

extern "C" void kernel_launch(void* const* d_in, const int* in_sizes, int n_in,
                              void* d_out, int out_size, void* d_ws, size_t ws_size,
                              hipStream_t stream) {
    const float* x        = (const float*)d_in[0];
    const int*   src      = (const int*)d_in[1];
    const int*   dst      = (const int*)d_in[2];
    const int*   graphids = (const int*)d_in[3];
    // d_in[4] = num_graphs scalar (256, hardcoded)
    const float* W0n   = (const float*)d_in[5];
    const float* b0    = (const float*)d_in[6];
    const float* W0s   = (const float*)d_in[7];
    const float* Wkn   = (const float*)d_in[8];
    const float* bk    = (const float*)d_in[9];
    const float* Wks   = (const float*)d_in[10];
    const float* fc1_w = (const float*)d_in[11];
    const float* fc1_b = (const float*)d_in[12];
    const float* out_w = (const float*)d_in[13];
    const float* out_b = (const float*)d_in[14];
    float* out = (float*)d_out;

    const int n_nodes = in_sizes[0] / 8;
    const int n_edges = in_sizes[1];
    const int nquads  = n_edges >> 2;

    const size_t NB = (size_t)n_nodes * sizeof(float);
    char* ws   = (char*)d_ws;
    float* agg = (float*)(ws);
    float* h   = (float*)(ws + NB);
    float* xw0 = (float*)(ws + 2 * NB);
    float* s0  = (float*)(ws + 3 * NB);
    float* hg  = (float*)(ws + 4 * NB);

    hipMemsetAsync(agg, 0, NB, stream);
    hipMemsetAsync(hg, 0, NGRAPHS * sizeof(float), stream);

    const int TB = 256;
    const int node_blocks = (n_nodes + TB - 1) / TB;
    const int edge_blocks = (nquads + TB - 1) / TB;

    node_init<<<node_blocks, TB, 0, stream>>>((const float4*)x, W0n, W0s, xw0, s0, n_nodes);

    // Layer 0
    edge_scatter<<<edge_blocks, TB, 0, stream>>>((const int4*)src, (const int4*)dst, xw0, agg, nquads);
    node_l0<<<node_blocks, TB, 0, stream>>>(agg, s0, b0, h, n_nodes);

    // Layers 1..2
    for (int li = 0; li < 2; ++li) {
        edge_scatter<<<edge_blocks, TB, 0, stream>>>((const int4*)src, (const int4*)dst, h, agg, nquads);
        node_lk<<<node_blocks, TB, 0, stream>>>(agg, h, Wkn, bk, Wks, li, n_nodes);
    }

    // Layer 3 + readout
    edge_scatter<<<edge_blocks, TB, 0, stream>>>((const int4*)src, (const int4*)dst, h, agg, nquads);
    node_l3_readout<<<node_blocks, TB, 0, stream>>>(agg, h, graphids, Wkn, bk, Wks, hg, n_nodes);

    head<<<1, TB, 0, stream>>>(hg, fc1_w, fc1_b, out_w, out_b, out);
}

// Round 2
// 736.152 us; speedup vs baseline: 4.3346x; 4.3346x over previous
//
#include <hip/hip_runtime.h>
#include <stdint.h>

// GCN, DIM=1. Strategy: bucket-sort edges by dst (1024-node buckets) once per
// call, then each of the 4 layers aggregates in LDS (no global atomics) with
// the node update fused into the flush. Fallback to the global-atomic path if
// the workspace is too small.

static constexpr int NGRAPHS    = 256;
static constexpr int TB         = 256;
static constexpr int BNODE_LOG  = 10;
static constexpr int BNODE      = 1 << BNODE_LOG;   // nodes per bucket
static constexpr int MAXBUCK    = 1024;
static constexpr int CHUNK      = 16384;            // edges per placement block

// ---------------- common kernels ----------------

__global__ void node_init(const float4* __restrict__ x,
                          const float* __restrict__ W0n,
                          const float* __restrict__ W0s,
                          float* __restrict__ xw0,
                          float* __restrict__ s0,
                          int n_nodes) {
    int n = blockIdx.x * blockDim.x + threadIdx.x;
    if (n >= n_nodes) return;
    float4 a = x[2 * n];
    float4 b = x[2 * n + 1];
    float xn = a.x * W0n[0] + a.y * W0n[1] + a.z * W0n[2] + a.w * W0n[3] +
               b.x * W0n[4] + b.y * W0n[5] + b.z * W0n[6] + b.w * W0n[7];
    float xs = a.x * W0s[0] + a.y * W0s[1] + a.z * W0s[2] + a.w * W0s[3] +
               b.x * W0s[4] + b.y * W0s[5] + b.z * W0s[6] + b.w * W0s[7];
    xw0[n] = xn;
    s0[n] = xs;
}

__global__ void head(const float* __restrict__ hg,
                     const float* __restrict__ fc1_w,
                     const float* __restrict__ fc1_b,
                     const float* __restrict__ out_w,
                     const float* __restrict__ out_b,
                     float* __restrict__ out) {
    int gph = threadIdx.x;
    if (gph >= NGRAPHS) return;
    float hv = hg[gph];
    float o0 = out_b[0], o1 = out_b[1], o2 = out_b[2], o3 = out_b[3];
#pragma unroll
    for (int j = 0; j < 8; ++j) {
        float z = (hv * fc1_w[j] + fc1_b[j]) * 1000.0f;
        float sg = 1.0f / (1.0f + expf(-z));
        o0 += sg * out_w[j * 4 + 0];
        o1 += sg * out_w[j * 4 + 1];
        o2 += sg * out_w[j * 4 + 2];
        o3 += sg * out_w[j * 4 + 3];
    }
    o0 = fmaxf(o0, 0.0f); o1 = fmaxf(o1, 0.0f);
    o2 = fmaxf(o2, 0.0f); o3 = fmaxf(o3, 0.0f);
    float m = fmaxf(fmaxf(o0, o1), fmaxf(o2, o3));
    float s = expf(o0 - m) + expf(o1 - m) + expf(o2 - m) + expf(o3 - m);
    float l = logf(s);
    out[gph * 4 + 0] = o0 - m - l;
    out[gph * 4 + 1] = o1 - m - l;
    out[gph * 4 + 2] = o2 - m - l;
    out[gph * 4 + 3] = o3 - m - l;
}

// ---------------- fast path: bucket build ----------------

__global__ void count_bins(const int* __restrict__ dst, int n_edges, int nbuck,
                           int* __restrict__ counts) {
    __shared__ int hist[MAXBUCK];
    for (int i = threadIdx.x; i < MAXBUCK; i += blockDim.x) hist[i] = 0;
    __syncthreads();
    int gtid = blockIdx.x * blockDim.x + threadIdx.x;
    int stride = gridDim.x * blockDim.x;
    for (int e = gtid; e < n_edges; e += stride)
        atomicAdd(&hist[dst[e] >> BNODE_LOG], 1);
    __syncthreads();
    for (int i = threadIdx.x; i < nbuck; i += blockDim.x)
        if (hist[i]) atomicAdd(&counts[i], hist[i]);
}

__global__ void scan_offsets(const int* __restrict__ counts, int nbuck,
                             int* __restrict__ offs, int* __restrict__ cursor) {
    __shared__ int lds[MAXBUCK];
    int i = threadIdx.x;
    int c = (i < nbuck) ? counts[i] : 0;
    lds[i] = c;
    __syncthreads();
    for (int off = 1; off < MAXBUCK; off <<= 1) {
        int v = (i >= off) ? lds[i - off] : 0;
        __syncthreads();
        lds[i] += v;
        __syncthreads();
    }
    int excl = lds[i] - c;           // exclusive prefix; for i >= nbuck this is total
    offs[i] = excl;
    if (i < nbuck) cursor[i] = excl;
    if (i == MAXBUCK - 1) offs[MAXBUCK] = lds[MAXBUCK - 1];
}

__global__ void place_edges(const int* __restrict__ src,
                            const int* __restrict__ dst,
                            int n_edges, int nbuck,
                            int* __restrict__ cursor,
                            uint32_t* __restrict__ sorted) {
    __shared__ int hist[MAXBUCK];
    for (int i = threadIdx.x; i < MAXBUCK; i += blockDim.x) hist[i] = 0;
    __syncthreads();
    int base = blockIdx.x * CHUNK;
    // phase A: local histogram of this chunk
    for (int k = 0; k < CHUNK; k += TB) {
        int e = base + k + threadIdx.x;
        if (e < n_edges) atomicAdd(&hist[dst[e] >> BNODE_LOG], 1);
    }
    __syncthreads();
    // phase B: reserve global ranges per bucket
    for (int t = threadIdx.x; t < nbuck; t += blockDim.x) {
        int h = hist[t];
        hist[t] = h ? atomicAdd(&cursor[t], h) : 0;
    }
    __syncthreads();
    // phase C: place packed edges
    for (int k = 0; k < CHUNK; k += TB) {
        int e = base + k + threadIdx.x;
        if (e < n_edges) {
            int d = dst[e];
            int b = d >> BNODE_LOG;
            int pos = atomicAdd(&hist[b], 1);
            sorted[pos] = ((uint32_t)(d & (BNODE - 1)) << 20) | (uint32_t)src[e];
        }
    }
}

// ---------------- fast path: per-layer aggregate (LDS) ----------------

__device__ __forceinline__ void bucket_accumulate(const uint32_t* __restrict__ sorted,
                                                  const int* __restrict__ offs,
                                                  const float* __restrict__ gsrc,
                                                  float* acc) {
    int b = blockIdx.x;
    for (int i = threadIdx.x; i < BNODE; i += TB) acc[i] = 0.0f;
    __syncthreads();
    int e = offs[b] + threadIdx.x;
    int eend = offs[b + 1];
    for (; e + 3 * TB < eend; e += 4 * TB) {
        uint32_t p0 = sorted[e];
        uint32_t p1 = sorted[e + TB];
        uint32_t p2 = sorted[e + 2 * TB];
        uint32_t p3 = sorted[e + 3 * TB];
        float v0 = gsrc[p0 & 0xFFFFFu];
        float v1 = gsrc[p1 & 0xFFFFFu];
        float v2 = gsrc[p2 & 0xFFFFFu];
        float v3 = gsrc[p3 & 0xFFFFFu];
        atomicAdd(&acc[p0 >> 20], v0);
        atomicAdd(&acc[p1 >> 20], v1);
        atomicAdd(&acc[p2 >> 20], v2);
        atomicAdd(&acc[p3 >> 20], v3);
    }
    for (; e < eend; e += TB) {
        uint32_t p = sorted[e];
        atomicAdd(&acc[p >> 20], gsrc[p & 0xFFFFFu]);
    }
    __syncthreads();
}

__global__ void layer0_agg(const uint32_t* __restrict__ sorted,
                           const int* __restrict__ offs,
                           const float* __restrict__ xw0,
                           const float* __restrict__ s0,
                           const float* __restrict__ b0,
                           float* __restrict__ h_out,
                           int n_nodes) {
    __shared__ float acc[BNODE];
    bucket_accumulate(sorted, offs, xw0, acc);
    int base = blockIdx.x << BNODE_LOG;
    int nloc = min(BNODE, n_nodes - base);
    float bb = b0[0];
    for (int i = threadIdx.x; i < nloc; i += TB) {
        int n = base + i;
        h_out[n] = fmaxf(acc[i] + bb + s0[n], 0.0f);
    }
}

__global__ void layerk_agg(const uint32_t* __restrict__ sorted,
                           const int* __restrict__ offs,
                           const float* __restrict__ h_in,
                           const float* __restrict__ Wkn,
                           const float* __restrict__ bk,
                           const float* __restrict__ Wks,
                           int li,
                           float* __restrict__ h_out,
                           int n_nodes) {
    __shared__ float acc[BNODE];
    bucket_accumulate(sorted, offs, h_in, acc);
    int base = blockIdx.x << BNODE_LOG;
    int nloc = min(BNODE, n_nodes - base);
    float wn = Wkn[li], bb = bk[li], ws = Wks[li];
    for (int i = threadIdx.x; i < nloc; i += TB) {
        int n = base + i;
        h_out[n] = fmaxf(wn * acc[i] + bb + ws * h_in[n], 0.0f);
    }
}

__global__ void layer_last_readout(const uint32_t* __restrict__ sorted,
                                   const int* __restrict__ offs,
                                   const float* __restrict__ h_in,
                                   const int* __restrict__ graph_ids,
                                   const float* __restrict__ Wkn,
                                   const float* __restrict__ bk,
                                   const float* __restrict__ Wks,
                                   int li,
                                   float* __restrict__ hg,
                                   int n_nodes) {
    __shared__ float acc[BNODE];
    bucket_accumulate(sorted, offs, h_in, acc);
    int base = blockIdx.x << BNODE_LOG;
    int nloc = min(BNODE, n_nodes - base);
    float wn = Wkn[li], bb = bk[li], ws = Wks[li];
    for (int i = threadIdx.x; i < BNODE; i += TB) {   // uniform bound for wave ops
        float val = 0.0f;
        int g = -1;
        if (i < nloc) {
            int n = base + i;
            val = fmaxf(wn * acc[i] + bb + ws * h_in[n], 0.0f);
            g = graph_ids[n];
        }
        int g0 = __shfl(g, 0);
        unsigned long long same = __ballot(g == g0);
        if (same == ~0ULL) {
            for (int o = 32; o > 0; o >>= 1) val += __shfl_down(val, o);
            if ((threadIdx.x & 63) == 0 && g >= 0) atomicAdd(&hg[g], val);
        } else if (g >= 0) {
            atomicAdd(&hg[g], val);
        }
    }
}

// ---------------- fallback path (round-1 global-atomic version) ----------------

__global__ void edge_scatter(const int4* __restrict__ src4,
                             const int4* __restrict__ dst4,
                             const float* __restrict__ val,
                             float* __restrict__ agg,
                             int nquads) {
    int t = blockIdx.x * blockDim.x + threadIdx.x;
    if (t >= nquads) return;
    int4 s = src4[t];
    int4 d = dst4[t];
    float v0 = val[s.x], v1 = val[s.y], v2 = val[s.z], v3 = val[s.w];
    atomicAdd(&agg[d.x], v0);
    atomicAdd(&agg[d.y], v1);
    atomicAdd(&agg[d.z], v2);
    atomicAdd(&agg[d.w], v3);
}

__global__ void node_l0(float* __restrict__ agg, const float* __restrict__ s0,
                        const float* __restrict__ b0, float* __restrict__ h, int n_nodes) {
    int n = blockIdx.x * blockDim.x + threadIdx.x;
    if (n >= n_nodes) return;
    h[n] = fmaxf(agg[n] + b0[0] + s0[n], 0.0f);
    agg[n] = 0.0f;
}

__global__ void node_lk(float* __restrict__ agg, float* __restrict__ h,
                        const float* __restrict__ Wkn, const float* __restrict__ bk,
                        const float* __restrict__ Wks, int li, int n_nodes) {
    int n = blockIdx.x * blockDim.x + threadIdx.x;
    if (n >= n_nodes) return;
    float v = Wkn[li] * agg[n] + bk[li] + Wks[li] * h[n];
    h[n] = fmaxf(v, 0.0f);
    agg[n] = 0.0f;
}

__global__ void node_l3_readout(const float* __restrict__ agg, const float* __restrict__ h,
                                const int* __restrict__ graph_ids,
                                const float* __restrict__ Wkn, const float* __restrict__ bk,
                                const float* __restrict__ Wks, float* __restrict__ hg,
                                int n_nodes) {
    int n = blockIdx.x * blockDim.x + threadIdx.x;
    float val = 0.0f;
    int g = -1;
    if (n < n_nodes) {
        val = fmaxf(Wkn[2] * agg[n] + bk[2] + Wks[2] * h[n], 0.0f);
        g = graph_ids[n];
    }
    int g0 = __shfl(g, 0);
    unsigned long long same = __ballot(g == g0);
    if (same == ~0ULL) {
        for (int o = 32; o > 0; o >>= 1) val += __shfl_down(val, o);
        if ((threadIdx.x & 63) == 0 && g >= 0) atomicAdd(&hg[g], val);
    } else if (g >= 0) {
        atomicAdd(&hg[g], val);
    }
}

// ---------------- launch ----------------

extern "C" void kernel_launch(void* const* d_in, const int* in_sizes, int n_in,
                              void* d_out, int out_size, void* d_ws, size_t ws_size,
                              hipStream_t stream) {
    const float* x        = (const float*)d_in[0];
    const int*   src      = (const int*)d_in[1];
    const int*   dst      = (const int*)d_in[2];
    const int*   graphids = (const int*)d_in[3];
    const float* W0n   = (const float*)d_in[5];
    const float* b0    = (const float*)d_in[6];
    const float* W0s   = (const float*)d_in[7];
    const float* Wkn   = (const float*)d_in[8];
    const float* bk    = (const float*)d_in[9];
    const float* Wks   = (const float*)d_in[10];
    const float* fc1_w = (const float*)d_in[11];
    const float* fc1_b = (const float*)d_in[12];
    const float* out_w = (const float*)d_in[13];
    const float* out_b = (const float*)d_in[14];
    float* out = (float*)d_out;

    const int n_nodes = in_sizes[0] / 8;
    const int n_edges = in_sizes[1];
    const int nbuck   = (n_nodes + BNODE - 1) >> BNODE_LOG;
    const int nchunks = (n_edges + CHUNK - 1) / CHUNK;
    const size_t NB   = (size_t)n_nodes * sizeof(float);

    const int node_blocks = (n_nodes + TB - 1) / TB;

    const size_t need = (size_t)n_edges * 4 + 4 * NB +
                        (MAXBUCK + (MAXBUCK + 1) + MAXBUCK + NGRAPHS) * sizeof(int) + 256;

    if (nbuck <= MAXBUCK && n_nodes <= (1 << 20) && ws_size >= need) {
        // ---- fast path ----
        char* ws = (char*)d_ws;
        uint32_t* sorted = (uint32_t*)ws;                 ws += (size_t)n_edges * 4;
        float* xw0 = (float*)ws;                          ws += NB;
        float* s0  = (float*)ws;                          ws += NB;
        float* h_a = (float*)ws;                          ws += NB;
        float* h_b = (float*)ws;                          ws += NB;
        int* counts = (int*)ws;                           ws += MAXBUCK * sizeof(int);
        int* offs   = (int*)ws;                           ws += (MAXBUCK + 1) * sizeof(int);
        int* cursor = (int*)ws;                           ws += MAXBUCK * sizeof(int);
        float* hg   = (float*)ws;

        hipMemsetAsync(counts, 0, nbuck * sizeof(int), stream);
        hipMemsetAsync(hg, 0, NGRAPHS * sizeof(float), stream);

        node_init<<<node_blocks, TB, 0, stream>>>((const float4*)x, W0n, W0s, xw0, s0, n_nodes);
        count_bins<<<2048, TB, 0, stream>>>(dst, n_edges, nbuck, counts);
        scan_offsets<<<1, MAXBUCK, 0, stream>>>(counts, nbuck, offs, cursor);
        place_edges<<<nchunks, TB, 0, stream>>>(src, dst, n_edges, nbuck, cursor, sorted);

        layer0_agg<<<nbuck, TB, 0, stream>>>(sorted, offs, xw0, s0, b0, h_a, n_nodes);
        layerk_agg<<<nbuck, TB, 0, stream>>>(sorted, offs, h_a, Wkn, bk, Wks, 0, h_b, n_nodes);
        layerk_agg<<<nbuck, TB, 0, stream>>>(sorted, offs, h_b, Wkn, bk, Wks, 1, h_a, n_nodes);
        layer_last_readout<<<nbuck, TB, 0, stream>>>(sorted, offs, h_a, graphids, Wkn, bk, Wks, 2, hg, n_nodes);

        head<<<1, TB, 0, stream>>>(hg, fc1_w, fc1_b, out_w, out_b, out);
    } else {
        // ---- fallback: global-atomic path ----
        char* ws   = (char*)d_ws;
        float* agg = (float*)(ws);
        float* h   = (float*)(ws + NB);
        float* xw0 = (float*)(ws + 2 * NB);
        float* s0  = (float*)(ws + 3 * NB);
        float* hg  = (float*)(ws + 4 * NB);
        const int nquads = n_edges >> 2;
        const int edge_blocks = (nquads + TB - 1) / TB;

        hipMemsetAsync(agg, 0, NB, stream);
        hipMemsetAsync(hg, 0, NGRAPHS * sizeof(float), stream);

        node_init<<<node_blocks, TB, 0, stream>>>((const float4*)x, W0n, W0s, xw0, s0, n_nodes);
        edge_scatter<<<edge_blocks, TB, 0, stream>>>((const int4*)src, (const int4*)dst, xw0, agg, nquads);
        node_l0<<<node_blocks, TB, 0, stream>>>(agg, s0, b0, h, n_nodes);
        for (int li = 0; li < 2; ++li) {
            edge_scatter<<<edge_blocks, TB, 0, stream>>>((const int4*)src, (const int4*)dst, h, agg, nquads);
            node_lk<<<node_blocks, TB, 0, stream>>>(agg, h, Wkn, bk, Wks, li, n_nodes);
        }
        edge_scatter<<<edge_blocks, TB, 0, stream>>>((const int4*)src, (const int4*)dst, h, agg, nquads);
        node_l3_readout<<<node_blocks, TB, 0, stream>>>(agg, h, graphids, Wkn, bk, Wks, hg, n_nodes);
        head<<<1, TB, 0, stream>>>(hg, fc1_w, fc1_b, out_w, out_b, out);
    }
}

// Round 3
// 651.630 us; speedup vs baseline: 4.8968x; 1.1297x over previous
//
#include <hip/hip_runtime.h>
#include <stdint.h>

// GCN, DIM=1. Bucket-sort edges by dst (1024-node buckets) once per call,
// then 4 layers aggregate in LDS (no global atomics), node update fused into
// the flush. Placement uses a 256-block grid so each XCD's active write-line
// working set (resident blocks x 1024 bucket lines) fits in its 4MB L2.

static constexpr int NGRAPHS    = 256;
static constexpr int TB         = 256;
static constexpr int TB_P       = 512;              // placement block size
static constexpr int PGRID      = 256;              // placement grid (1 block/CU)
static constexpr int BNODE_LOG  = 10;
static constexpr int BNODE      = 1 << BNODE_LOG;   // nodes per bucket
static constexpr int MAXBUCK    = 1024;

// ---------------- common kernels ----------------

__global__ void node_init(const float4* __restrict__ x,
                          const float* __restrict__ W0n,
                          const float* __restrict__ W0s,
                          float* __restrict__ xw0,
                          float* __restrict__ s0,
                          int n_nodes) {
    int n = blockIdx.x * blockDim.x + threadIdx.x;
    if (n >= n_nodes) return;
    float4 a = x[2 * n];
    float4 b = x[2 * n + 1];
    float xn = a.x * W0n[0] + a.y * W0n[1] + a.z * W0n[2] + a.w * W0n[3] +
               b.x * W0n[4] + b.y * W0n[5] + b.z * W0n[6] + b.w * W0n[7];
    float xs = a.x * W0s[0] + a.y * W0s[1] + a.z * W0s[2] + a.w * W0s[3] +
               b.x * W0s[4] + b.y * W0s[5] + b.z * W0s[6] + b.w * W0s[7];
    xw0[n] = xn;
    s0[n] = xs;
}

__global__ void head(const float* __restrict__ hg,
                     const float* __restrict__ fc1_w,
                     const float* __restrict__ fc1_b,
                     const float* __restrict__ out_w,
                     const float* __restrict__ out_b,
                     float* __restrict__ out) {
    int gph = threadIdx.x;
    if (gph >= NGRAPHS) return;
    float hv = hg[gph];
    float o0 = out_b[0], o1 = out_b[1], o2 = out_b[2], o3 = out_b[3];
#pragma unroll
    for (int j = 0; j < 8; ++j) {
        float z = (hv * fc1_w[j] + fc1_b[j]) * 1000.0f;
        float sg = 1.0f / (1.0f + expf(-z));
        o0 += sg * out_w[j * 4 + 0];
        o1 += sg * out_w[j * 4 + 1];
        o2 += sg * out_w[j * 4 + 2];
        o3 += sg * out_w[j * 4 + 3];
    }
    o0 = fmaxf(o0, 0.0f); o1 = fmaxf(o1, 0.0f);
    o2 = fmaxf(o2, 0.0f); o3 = fmaxf(o3, 0.0f);
    float m = fmaxf(fmaxf(o0, o1), fmaxf(o2, o3));
    float s = expf(o0 - m) + expf(o1 - m) + expf(o2 - m) + expf(o3 - m);
    float l = logf(s);
    out[gph * 4 + 0] = o0 - m - l;
    out[gph * 4 + 1] = o1 - m - l;
    out[gph * 4 + 2] = o2 - m - l;
    out[gph * 4 + 3] = o3 - m - l;
}

// ---------------- bucket build ----------------

__global__ void count_bins(const int* __restrict__ dst, int n_edges, int nbuck,
                           int* __restrict__ counts) {
    __shared__ int hist[MAXBUCK];
    for (int i = threadIdx.x; i < MAXBUCK; i += blockDim.x) hist[i] = 0;
    __syncthreads();
    int gtid = blockIdx.x * blockDim.x + threadIdx.x;
    int stride = gridDim.x * blockDim.x;
    for (int e = gtid; e < n_edges; e += stride)
        atomicAdd(&hist[dst[e] >> BNODE_LOG], 1);
    __syncthreads();
    for (int i = threadIdx.x; i < nbuck; i += blockDim.x)
        if (hist[i]) atomicAdd(&counts[i], hist[i]);
}

__global__ void scan_offsets(const int* __restrict__ counts, int nbuck,
                             int* __restrict__ offs, int* __restrict__ cursor) {
    __shared__ int lds[MAXBUCK];
    int i = threadIdx.x;
    int c = (i < nbuck) ? counts[i] : 0;
    lds[i] = c;
    __syncthreads();
    for (int off = 1; off < MAXBUCK; off <<= 1) {
        int v = (i >= off) ? lds[i - off] : 0;
        __syncthreads();
        lds[i] += v;
        __syncthreads();
    }
    int excl = lds[i] - c;
    offs[i] = excl;
    if (i < nbuck) cursor[i] = excl;
    if (i == MAXBUCK - 1) offs[MAXBUCK] = lds[MAXBUCK - 1];
}

// One block per mega-chunk, PGRID blocks total so the per-XCD set of active
// write lines (resident_blocks_per_xcd * nbuck * 64B) fits in the 4MB L2.
__global__ void place_edges(const int* __restrict__ src,
                            const int* __restrict__ dst,
                            int n_edges, int nbuck,
                            int* __restrict__ cursor,
                            uint32_t* __restrict__ sorted) {
    __shared__ int hist[MAXBUCK];
    for (int i = threadIdx.x; i < MAXBUCK; i += blockDim.x) hist[i] = 0;
    __syncthreads();

    const int nquads = n_edges >> 2;
    const int perq = (nquads + gridDim.x - 1) / gridDim.x;
    const int begq = blockIdx.x * perq;
    const int endq = min(begq + perq, nquads);
    const bool last = (blockIdx.x == gridDim.x - 1);
    const int tail_beg = nquads << 2;

    const int4* src4 = (const int4*)src;
    const int4* dst4 = (const int4*)dst;

    // phase A: chunk histogram
    for (int q = begq + threadIdx.x; q < endq; q += blockDim.x) {
        int4 d = dst4[q];
        atomicAdd(&hist[d.x >> BNODE_LOG], 1);
        atomicAdd(&hist[d.y >> BNODE_LOG], 1);
        atomicAdd(&hist[d.z >> BNODE_LOG], 1);
        atomicAdd(&hist[d.w >> BNODE_LOG], 1);
    }
    if (last) {
        for (int e = tail_beg + threadIdx.x; e < n_edges; e += blockDim.x)
            atomicAdd(&hist[dst[e] >> BNODE_LOG], 1);
    }
    __syncthreads();
    // phase B: reserve global subranges
    for (int b = threadIdx.x; b < nbuck; b += blockDim.x) {
        int h = hist[b];
        hist[b] = h ? atomicAdd(&cursor[b], h) : 0;
    }
    __syncthreads();
    // phase C: place packed edges
    for (int q = begq + threadIdx.x; q < endq; q += blockDim.x) {
        int4 d = dst4[q];
        int4 s = src4[q];
        int p0 = atomicAdd(&hist[d.x >> BNODE_LOG], 1);
        int p1 = atomicAdd(&hist[d.y >> BNODE_LOG], 1);
        int p2 = atomicAdd(&hist[d.z >> BNODE_LOG], 1);
        int p3 = atomicAdd(&hist[d.w >> BNODE_LOG], 1);
        sorted[p0] = ((uint32_t)(d.x & (BNODE - 1)) << 20) | (uint32_t)s.x;
        sorted[p1] = ((uint32_t)(d.y & (BNODE - 1)) << 20) | (uint32_t)s.y;
        sorted[p2] = ((uint32_t)(d.z & (BNODE - 1)) << 20) | (uint32_t)s.z;
        sorted[p3] = ((uint32_t)(d.w & (BNODE - 1)) << 20) | (uint32_t)s.w;
    }
    if (last) {
        for (int e = tail_beg + threadIdx.x; e < n_edges; e += blockDim.x) {
            int d = dst[e];
            int pos = atomicAdd(&hist[d >> BNODE_LOG], 1);
            sorted[pos] = ((uint32_t)(d & (BNODE - 1)) << 20) | (uint32_t)src[e];
        }
    }
}

// ---------------- per-layer aggregate (LDS) ----------------

__device__ __forceinline__ void bucket_accumulate(const uint32_t* __restrict__ sorted,
                                                  const int* __restrict__ offs,
                                                  const float* __restrict__ gsrc,
                                                  float* acc) {
    int b = blockIdx.x;
    for (int i = threadIdx.x; i < BNODE; i += TB) acc[i] = 0.0f;
    __syncthreads();
    int e = offs[b] + threadIdx.x;
    int eend = offs[b + 1];
    for (; e + 3 * TB < eend; e += 4 * TB) {
        uint32_t p0 = sorted[e];
        uint32_t p1 = sorted[e + TB];
        uint32_t p2 = sorted[e + 2 * TB];
        uint32_t p3 = sorted[e + 3 * TB];
        float v0 = gsrc[p0 & 0xFFFFFu];
        float v1 = gsrc[p1 & 0xFFFFFu];
        float v2 = gsrc[p2 & 0xFFFFFu];
        float v3 = gsrc[p3 & 0xFFFFFu];
        atomicAdd(&acc[p0 >> 20], v0);
        atomicAdd(&acc[p1 >> 20], v1);
        atomicAdd(&acc[p2 >> 20], v2);
        atomicAdd(&acc[p3 >> 20], v3);
    }
    for (; e < eend; e += TB) {
        uint32_t p = sorted[e];
        atomicAdd(&acc[p >> 20], gsrc[p & 0xFFFFFu]);
    }
    __syncthreads();
}

__global__ void layer0_agg(const uint32_t* __restrict__ sorted,
                           const int* __restrict__ offs,
                           const float* __restrict__ xw0,
                           const float* __restrict__ s0,
                           const float* __restrict__ b0,
                           float* __restrict__ h_out,
                           int n_nodes) {
    __shared__ float acc[BNODE];
    bucket_accumulate(sorted, offs, xw0, acc);
    int base = blockIdx.x << BNODE_LOG;
    int nloc = min(BNODE, n_nodes - base);
    float bb = b0[0];
    for (int i = threadIdx.x; i < nloc; i += TB) {
        int n = base + i;
        h_out[n] = fmaxf(acc[i] + bb + s0[n], 0.0f);
    }
}

__global__ void layerk_agg(const uint32_t* __restrict__ sorted,
                           const int* __restrict__ offs,
                           const float* __restrict__ h_in,
                           const float* __restrict__ Wkn,
                           const float* __restrict__ bk,
                           const float* __restrict__ Wks,
                           int li,
                           float* __restrict__ h_out,
                           int n_nodes) {
    __shared__ float acc[BNODE];
    bucket_accumulate(sorted, offs, h_in, acc);
    int base = blockIdx.x << BNODE_LOG;
    int nloc = min(BNODE, n_nodes - base);
    float wn = Wkn[li], bb = bk[li], ws = Wks[li];
    for (int i = threadIdx.x; i < nloc; i += TB) {
        int n = base + i;
        h_out[n] = fmaxf(wn * acc[i] + bb + ws * h_in[n], 0.0f);
    }
}

__global__ void layer_last_readout(const uint32_t* __restrict__ sorted,
                                   const int* __restrict__ offs,
                                   const float* __restrict__ h_in,
                                   const int* __restrict__ graph_ids,
                                   const float* __restrict__ Wkn,
                                   const float* __restrict__ bk,
                                   const float* __restrict__ Wks,
                                   int li,
                                   float* __restrict__ hg,
                                   int n_nodes) {
    __shared__ float acc[BNODE];
    bucket_accumulate(sorted, offs, h_in, acc);
    int base = blockIdx.x << BNODE_LOG;
    int nloc = min(BNODE, n_nodes - base);
    float wn = Wkn[li], bb = bk[li], ws = Wks[li];
    for (int i = threadIdx.x; i < BNODE; i += TB) {   // uniform bound for wave ops
        float val = 0.0f;
        int g = -1;
        if (i < nloc) {
            int n = base + i;
            val = fmaxf(wn * acc[i] + bb + ws * h_in[n], 0.0f);
            g = graph_ids[n];
        }
        int g0 = __shfl(g, 0);
        unsigned long long same = __ballot(g == g0);
        if (same == ~0ULL) {
            for (int o = 32; o > 0; o >>= 1) val += __shfl_down(val, o);
            if ((threadIdx.x & 63) == 0 && g >= 0) atomicAdd(&hg[g], val);
        } else if (g >= 0) {
            atomicAdd(&hg[g], val);
        }
    }
}

// ---------------- fallback path (global atomics) ----------------

__global__ void edge_scatter(const int4* __restrict__ src4,
                             const int4* __restrict__ dst4,
                             const float* __restrict__ val,
                             float* __restrict__ agg,
                             int nquads) {
    int t = blockIdx.x * blockDim.x + threadIdx.x;
    if (t >= nquads) return;
    int4 s = src4[t];
    int4 d = dst4[t];
    float v0 = val[s.x], v1 = val[s.y], v2 = val[s.z], v3 = val[s.w];
    atomicAdd(&agg[d.x], v0);
    atomicAdd(&agg[d.y], v1);
    atomicAdd(&agg[d.z], v2);
    atomicAdd(&agg[d.w], v3);
}

__global__ void node_l0(float* __restrict__ agg, const float* __restrict__ s0,
                        const float* __restrict__ b0, float* __restrict__ h, int n_nodes) {
    int n = blockIdx.x * blockDim.x + threadIdx.x;
    if (n >= n_nodes) return;
    h[n] = fmaxf(agg[n] + b0[0] + s0[n], 0.0f);
    agg[n] = 0.0f;
}

__global__ void node_lk(float* __restrict__ agg, float* __restrict__ h,
                        const float* __restrict__ Wkn, const float* __restrict__ bk,
                        const float* __restrict__ Wks, int li, int n_nodes) {
    int n = blockIdx.x * blockDim.x + threadIdx.x;
    if (n >= n_nodes) return;
    float v = Wkn[li] * agg[n] + bk[li] + Wks[li] * h[n];
    h[n] = fmaxf(v, 0.0f);
    agg[n] = 0.0f;
}

__global__ void node_l3_readout(const float* __restrict__ agg, const float* __restrict__ h,
                                const int* __restrict__ graph_ids,
                                const float* __restrict__ Wkn, const float* __restrict__ bk,
                                const float* __restrict__ Wks, float* __restrict__ hg,
                                int n_nodes) {
    int n = blockIdx.x * blockDim.x + threadIdx.x;
    float val = 0.0f;
    int g = -1;
    if (n < n_nodes) {
        val = fmaxf(Wkn[2] * agg[n] + bk[2] + Wks[2] * h[n], 0.0f);
        g = graph_ids[n];
    }
    int g0 = __shfl(g, 0);
    unsigned long long same = __ballot(g == g0);
    if (same == ~0ULL) {
        for (int o = 32; o > 0; o >>= 1) val += __shfl_down(val, o);
        if ((threadIdx.x & 63) == 0 && g >= 0) atomicAdd(&hg[g], val);
    } else if (g >= 0) {
        atomicAdd(&hg[g], val);
    }
}

// ---------------- launch ----------------

extern "C" void kernel_launch(void* const* d_in, const int* in_sizes, int n_in,
                              void* d_out, int out_size, void* d_ws, size_t ws_size,
                              hipStream_t stream) {
    const float* x        = (const float*)d_in[0];
    const int*   src      = (const int*)d_in[1];
    const int*   dst      = (const int*)d_in[2];
    const int*   graphids = (const int*)d_in[3];
    const float* W0n   = (const float*)d_in[5];
    const float* b0    = (const float*)d_in[6];
    const float* W0s   = (const float*)d_in[7];
    const float* Wkn   = (const float*)d_in[8];
    const float* bk    = (const float*)d_in[9];
    const float* Wks   = (const float*)d_in[10];
    const float* fc1_w = (const float*)d_in[11];
    const float* fc1_b = (const float*)d_in[12];
    const float* out_w = (const float*)d_in[13];
    const float* out_b = (const float*)d_in[14];
    float* out = (float*)d_out;

    const int n_nodes = in_sizes[0] / 8;
    const int n_edges = in_sizes[1];
    const int nbuck   = (n_nodes + BNODE - 1) >> BNODE_LOG;
    const size_t NB   = (size_t)n_nodes * sizeof(float);

    const int node_blocks = (n_nodes + TB - 1) / TB;

    const size_t need = (size_t)n_edges * 4 + 4 * NB +
                        (MAXBUCK + (MAXBUCK + 1) + MAXBUCK + NGRAPHS) * sizeof(int) + 256;

    if (nbuck <= MAXBUCK && n_nodes <= (1 << 20) && ws_size >= need) {
        // ---- fast path ----
        char* ws = (char*)d_ws;
        uint32_t* sorted = (uint32_t*)ws;                 ws += (size_t)n_edges * 4;
        float* xw0 = (float*)ws;                          ws += NB;
        float* s0  = (float*)ws;                          ws += NB;
        float* h_a = (float*)ws;                          ws += NB;
        float* h_b = (float*)ws;                          ws += NB;
        int* counts = (int*)ws;                           ws += MAXBUCK * sizeof(int);
        int* offs   = (int*)ws;                           ws += (MAXBUCK + 1) * sizeof(int);
        int* cursor = (int*)ws;                           ws += MAXBUCK * sizeof(int);
        float* hg   = (float*)ws;

        hipMemsetAsync(counts, 0, nbuck * sizeof(int), stream);
        hipMemsetAsync(hg, 0, NGRAPHS * sizeof(float), stream);

        node_init<<<node_blocks, TB, 0, stream>>>((const float4*)x, W0n, W0s, xw0, s0, n_nodes);
        count_bins<<<2048, TB, 0, stream>>>(dst, n_edges, nbuck, counts);
        scan_offsets<<<1, MAXBUCK, 0, stream>>>(counts, nbuck, offs, cursor);
        place_edges<<<PGRID, TB_P, 0, stream>>>(src, dst, n_edges, nbuck, cursor, sorted);

        layer0_agg<<<nbuck, TB, 0, stream>>>(sorted, offs, xw0, s0, b0, h_a, n_nodes);
        layerk_agg<<<nbuck, TB, 0, stream>>>(sorted, offs, h_a, Wkn, bk, Wks, 0, h_b, n_nodes);
        layerk_agg<<<nbuck, TB, 0, stream>>>(sorted, offs, h_b, Wkn, bk, Wks, 1, h_a, n_nodes);
        layer_last_readout<<<nbuck, TB, 0, stream>>>(sorted, offs, h_a, graphids, Wkn, bk, Wks, 2, hg, n_nodes);

        head<<<1, TB, 0, stream>>>(hg, fc1_w, fc1_b, out_w, out_b, out);
    } else {
        // ---- fallback: global-atomic path ----
        char* ws   = (char*)d_ws;
        float* agg = (float*)(ws);
        float* h   = (float*)(ws + NB);
        float* xw0 = (float*)(ws + 2 * NB);
        float* s0  = (float*)(ws + 3 * NB);
        float* hg  = (float*)(ws + 4 * NB);
        const int nquads = n_edges >> 2;
        const int edge_blocks = (nquads + TB - 1) / TB;

        hipMemsetAsync(agg, 0, NB, stream);
        hipMemsetAsync(hg, 0, NGRAPHS * sizeof(float), stream);

        node_init<<<node_blocks, TB, 0, stream>>>((const float4*)x, W0n, W0s, xw0, s0, n_nodes);
        edge_scatter<<<edge_blocks, TB, 0, stream>>>((const int4*)src, (const int4*)dst, xw0, agg, nquads);
        node_l0<<<node_blocks, TB, 0, stream>>>(agg, s0, b0, h, n_nodes);
        for (int li = 0; li < 2; ++li) {
            edge_scatter<<<edge_blocks, TB, 0, stream>>>((const int4*)src, (const int4*)dst, h, agg, nquads);
            node_lk<<<node_blocks, TB, 0, stream>>>(agg, h, Wkn, bk, Wks, li, n_nodes);
        }
        edge_scatter<<<edge_blocks, TB, 0, stream>>>((const int4*)src, (const int4*)dst, h, agg, nquads);
        node_l3_readout<<<node_blocks, TB, 0, stream>>>(agg, h, graphids, Wkn, bk, Wks, hg, n_nodes);
        head<<<1, TB, 0, stream>>>(hg, fc1_w, fc1_b, out_w, out_b, out);
    }
}

// Round 4
// 596.871 us; speedup vs baseline: 5.3460x; 1.0917x over previous
//
#include <hip/hip_runtime.h>
#include <stdint.h>

// GCN, DIM=1. Bucket-sort edges by dst (4096-node buckets, 245 buckets) once
// per call, then 4 layers aggregate in LDS (no global atomics), node update
// fused into the flush. 4096-node buckets keep the placement write-line
// working set tiny (245 lines/block) so each sorted-output cache line is
// written back to HBM exactly once.

static constexpr int NGRAPHS    = 256;
static constexpr int TB         = 256;
static constexpr int TB_P       = 512;              // placement block size
static constexpr int PGRID      = 256;              // placement grid (1 block/CU)
static constexpr int TB_A       = 1024;             // aggregation block size
static constexpr int BNODE_LOG  = 12;
static constexpr int BNODE      = 1 << BNODE_LOG;   // nodes per bucket (4096)
static constexpr int MAXBUCK    = 256;
static constexpr int LOCAL_SHIFT = 20;              // local dst in bits 20..31

// ---------------- common kernels ----------------

__global__ void node_init(const float4* __restrict__ x,
                          const float* __restrict__ W0n,
                          const float* __restrict__ W0s,
                          float* __restrict__ xw0,
                          float* __restrict__ s0,
                          int n_nodes) {
    int n = blockIdx.x * blockDim.x + threadIdx.x;
    if (n >= n_nodes) return;
    float4 a = x[2 * n];
    float4 b = x[2 * n + 1];
    float xn = a.x * W0n[0] + a.y * W0n[1] + a.z * W0n[2] + a.w * W0n[3] +
               b.x * W0n[4] + b.y * W0n[5] + b.z * W0n[6] + b.w * W0n[7];
    float xs = a.x * W0s[0] + a.y * W0s[1] + a.z * W0s[2] + a.w * W0s[3] +
               b.x * W0s[4] + b.y * W0s[5] + b.z * W0s[6] + b.w * W0s[7];
    xw0[n] = xn;
    s0[n] = xs;
}

__global__ void head(const float* __restrict__ hg,
                     const float* __restrict__ fc1_w,
                     const float* __restrict__ fc1_b,
                     const float* __restrict__ out_w,
                     const float* __restrict__ out_b,
                     float* __restrict__ out) {
    int gph = threadIdx.x;
    if (gph >= NGRAPHS) return;
    float hv = hg[gph];
    float o0 = out_b[0], o1 = out_b[1], o2 = out_b[2], o3 = out_b[3];
#pragma unroll
    for (int j = 0; j < 8; ++j) {
        float z = (hv * fc1_w[j] + fc1_b[j]) * 1000.0f;
        float sg = 1.0f / (1.0f + expf(-z));
        o0 += sg * out_w[j * 4 + 0];
        o1 += sg * out_w[j * 4 + 1];
        o2 += sg * out_w[j * 4 + 2];
        o3 += sg * out_w[j * 4 + 3];
    }
    o0 = fmaxf(o0, 0.0f); o1 = fmaxf(o1, 0.0f);
    o2 = fmaxf(o2, 0.0f); o3 = fmaxf(o3, 0.0f);
    float m = fmaxf(fmaxf(o0, o1), fmaxf(o2, o3));
    float s = expf(o0 - m) + expf(o1 - m) + expf(o2 - m) + expf(o3 - m);
    float l = logf(s);
    out[gph * 4 + 0] = o0 - m - l;
    out[gph * 4 + 1] = o1 - m - l;
    out[gph * 4 + 2] = o2 - m - l;
    out[gph * 4 + 3] = o3 - m - l;
}

// ---------------- bucket build ----------------

__global__ void count_bins(const int* __restrict__ dst, int n_edges, int nbuck,
                           int* __restrict__ counts) {
    __shared__ int hist[MAXBUCK];
    for (int i = threadIdx.x; i < MAXBUCK; i += blockDim.x) hist[i] = 0;
    __syncthreads();
    const int4* dst4 = (const int4*)dst;
    int nquads = n_edges >> 2;
    int gtid = blockIdx.x * blockDim.x + threadIdx.x;
    int stride = gridDim.x * blockDim.x;
    for (int q = gtid; q < nquads; q += stride) {
        int4 d = dst4[q];
        atomicAdd(&hist[d.x >> BNODE_LOG], 1);
        atomicAdd(&hist[d.y >> BNODE_LOG], 1);
        atomicAdd(&hist[d.z >> BNODE_LOG], 1);
        atomicAdd(&hist[d.w >> BNODE_LOG], 1);
    }
    if (blockIdx.x == 0) {
        for (int e = (nquads << 2) + threadIdx.x; e < n_edges; e += blockDim.x)
            atomicAdd(&hist[dst[e] >> BNODE_LOG], 1);
    }
    __syncthreads();
    for (int i = threadIdx.x; i < nbuck; i += blockDim.x)
        if (hist[i]) atomicAdd(&counts[i], hist[i]);
}

__global__ void scan_offsets(const int* __restrict__ counts, int nbuck,
                             int* __restrict__ offs, int* __restrict__ cursor) {
    __shared__ int lds[MAXBUCK];
    int i = threadIdx.x;
    int c = (i < nbuck) ? counts[i] : 0;
    lds[i] = c;
    __syncthreads();
    for (int off = 1; off < MAXBUCK; off <<= 1) {
        int v = (i >= off) ? lds[i - off] : 0;
        __syncthreads();
        lds[i] += v;
        __syncthreads();
    }
    int excl = lds[i] - c;
    offs[i] = excl;
    if (i < nbuck) cursor[i] = excl;
    if (i == MAXBUCK - 1) offs[MAXBUCK] = lds[MAXBUCK - 1];
}

// One block per mega-chunk, PGRID blocks total. 245 active write lines per
// block (16KB); per-XCD active+streamed working set << 4MB L2, so each
// sorted-output line is written back once.
__global__ void place_edges(const int* __restrict__ src,
                            const int* __restrict__ dst,
                            int n_edges, int nbuck,
                            int* __restrict__ cursor,
                            uint32_t* __restrict__ sorted) {
    __shared__ int hist[MAXBUCK];
    for (int i = threadIdx.x; i < MAXBUCK; i += blockDim.x) hist[i] = 0;
    __syncthreads();

    const int nquads = n_edges >> 2;
    const int perq = (nquads + gridDim.x - 1) / gridDim.x;
    const int begq = blockIdx.x * perq;
    const int endq = min(begq + perq, nquads);
    const bool last = (blockIdx.x == gridDim.x - 1);
    const int tail_beg = nquads << 2;

    const int4* src4 = (const int4*)src;
    const int4* dst4 = (const int4*)dst;

    // phase A: chunk histogram
    for (int q = begq + threadIdx.x; q < endq; q += blockDim.x) {
        int4 d = dst4[q];
        atomicAdd(&hist[d.x >> BNODE_LOG], 1);
        atomicAdd(&hist[d.y >> BNODE_LOG], 1);
        atomicAdd(&hist[d.z >> BNODE_LOG], 1);
        atomicAdd(&hist[d.w >> BNODE_LOG], 1);
    }
    if (last) {
        for (int e = tail_beg + threadIdx.x; e < n_edges; e += blockDim.x)
            atomicAdd(&hist[dst[e] >> BNODE_LOG], 1);
    }
    __syncthreads();
    // phase B: reserve global subranges
    for (int b = threadIdx.x; b < nbuck; b += blockDim.x) {
        int h = hist[b];
        hist[b] = h ? atomicAdd(&cursor[b], h) : 0;
    }
    __syncthreads();
    // phase C: place packed edges
    for (int q = begq + threadIdx.x; q < endq; q += blockDim.x) {
        int4 d = dst4[q];
        int4 s = src4[q];
        int p0 = atomicAdd(&hist[d.x >> BNODE_LOG], 1);
        int p1 = atomicAdd(&hist[d.y >> BNODE_LOG], 1);
        int p2 = atomicAdd(&hist[d.z >> BNODE_LOG], 1);
        int p3 = atomicAdd(&hist[d.w >> BNODE_LOG], 1);
        sorted[p0] = ((uint32_t)(d.x & (BNODE - 1)) << LOCAL_SHIFT) | (uint32_t)s.x;
        sorted[p1] = ((uint32_t)(d.y & (BNODE - 1)) << LOCAL_SHIFT) | (uint32_t)s.y;
        sorted[p2] = ((uint32_t)(d.z & (BNODE - 1)) << LOCAL_SHIFT) | (uint32_t)s.z;
        sorted[p3] = ((uint32_t)(d.w & (BNODE - 1)) << LOCAL_SHIFT) | (uint32_t)s.w;
    }
    if (last) {
        for (int e = tail_beg + threadIdx.x; e < n_edges; e += blockDim.x) {
            int d = dst[e];
            int pos = atomicAdd(&hist[d >> BNODE_LOG], 1);
            sorted[pos] = ((uint32_t)(d & (BNODE - 1)) << LOCAL_SHIFT) | (uint32_t)src[e];
        }
    }
}

// ---------------- per-layer aggregate (LDS) ----------------

__device__ __forceinline__ void bucket_accumulate(const uint32_t* __restrict__ sorted,
                                                  const int* __restrict__ offs,
                                                  const float* __restrict__ gsrc,
                                                  float* acc) {
    int b = blockIdx.x;
    for (int i = threadIdx.x; i < BNODE; i += TB_A) acc[i] = 0.0f;
    __syncthreads();
    int e = offs[b] + threadIdx.x;
    int eend = offs[b + 1];
    for (; e + 3 * TB_A < eend; e += 4 * TB_A) {
        uint32_t p0 = sorted[e];
        uint32_t p1 = sorted[e + TB_A];
        uint32_t p2 = sorted[e + 2 * TB_A];
        uint32_t p3 = sorted[e + 3 * TB_A];
        float v0 = gsrc[p0 & 0xFFFFFu];
        float v1 = gsrc[p1 & 0xFFFFFu];
        float v2 = gsrc[p2 & 0xFFFFFu];
        float v3 = gsrc[p3 & 0xFFFFFu];
        atomicAdd(&acc[p0 >> LOCAL_SHIFT], v0);
        atomicAdd(&acc[p1 >> LOCAL_SHIFT], v1);
        atomicAdd(&acc[p2 >> LOCAL_SHIFT], v2);
        atomicAdd(&acc[p3 >> LOCAL_SHIFT], v3);
    }
    for (; e < eend; e += TB_A) {
        uint32_t p = sorted[e];
        atomicAdd(&acc[p >> LOCAL_SHIFT], gsrc[p & 0xFFFFFu]);
    }
    __syncthreads();
}

__global__ void layer0_agg(const uint32_t* __restrict__ sorted,
                           const int* __restrict__ offs,
                           const float* __restrict__ xw0,
                           const float* __restrict__ s0,
                           const float* __restrict__ b0,
                           float* __restrict__ h_out,
                           int n_nodes) {
    __shared__ float acc[BNODE];
    bucket_accumulate(sorted, offs, xw0, acc);
    int base = blockIdx.x << BNODE_LOG;
    int nloc = min(BNODE, n_nodes - base);
    float bb = b0[0];
    for (int i = threadIdx.x; i < nloc; i += TB_A) {
        int n = base + i;
        h_out[n] = fmaxf(acc[i] + bb + s0[n], 0.0f);
    }
}

__global__ void layerk_agg(const uint32_t* __restrict__ sorted,
                           const int* __restrict__ offs,
                           const float* __restrict__ h_in,
                           const float* __restrict__ Wkn,
                           const float* __restrict__ bk,
                           const float* __restrict__ Wks,
                           int li,
                           float* __restrict__ h_out,
                           int n_nodes) {
    __shared__ float acc[BNODE];
    bucket_accumulate(sorted, offs, h_in, acc);
    int base = blockIdx.x << BNODE_LOG;
    int nloc = min(BNODE, n_nodes - base);
    float wn = Wkn[li], bb = bk[li], ws = Wks[li];
    for (int i = threadIdx.x; i < nloc; i += TB_A) {
        int n = base + i;
        h_out[n] = fmaxf(wn * acc[i] + bb + ws * h_in[n], 0.0f);
    }
}

__global__ void layer_last_readout(const uint32_t* __restrict__ sorted,
                                   const int* __restrict__ offs,
                                   const float* __restrict__ h_in,
                                   const int* __restrict__ graph_ids,
                                   const float* __restrict__ Wkn,
                                   const float* __restrict__ bk,
                                   const float* __restrict__ Wks,
                                   int li,
                                   float* __restrict__ hg,
                                   int n_nodes) {
    __shared__ float acc[BNODE];
    bucket_accumulate(sorted, offs, h_in, acc);
    int base = blockIdx.x << BNODE_LOG;
    int nloc = min(BNODE, n_nodes - base);
    float wn = Wkn[li], bb = bk[li], ws = Wks[li];
    for (int i = threadIdx.x; i < BNODE; i += TB_A) {   // uniform bound for wave ops
        float val = 0.0f;
        int g = -1;
        if (i < nloc) {
            int n = base + i;
            val = fmaxf(wn * acc[i] + bb + ws * h_in[n], 0.0f);
            g = graph_ids[n];
        }
        int g0 = __shfl(g, 0);
        unsigned long long same = __ballot(g == g0);
        if (same == ~0ULL) {
            for (int o = 32; o > 0; o >>= 1) val += __shfl_down(val, o);
            if ((threadIdx.x & 63) == 0 && g >= 0) atomicAdd(&hg[g], val);
        } else if (g >= 0) {
            atomicAdd(&hg[g], val);
        }
    }
}

// ---------------- fallback path (global atomics) ----------------

__global__ void edge_scatter(const int4* __restrict__ src4,
                             const int4* __restrict__ dst4,
                             const float* __restrict__ val,
                             float* __restrict__ agg,
                             int nquads) {
    int t = blockIdx.x * blockDim.x + threadIdx.x;
    if (t >= nquads) return;
    int4 s = src4[t];
    int4 d = dst4[t];
    float v0 = val[s.x], v1 = val[s.y], v2 = val[s.z], v3 = val[s.w];
    atomicAdd(&agg[d.x], v0);
    atomicAdd(&agg[d.y], v1);
    atomicAdd(&agg[d.z], v2);
    atomicAdd(&agg[d.w], v3);
}

__global__ void node_l0(float* __restrict__ agg, const float* __restrict__ s0,
                        const float* __restrict__ b0, float* __restrict__ h, int n_nodes) {
    int n = blockIdx.x * blockDim.x + threadIdx.x;
    if (n >= n_nodes) return;
    h[n] = fmaxf(agg[n] + b0[0] + s0[n], 0.0f);
    agg[n] = 0.0f;
}

__global__ void node_lk(float* __restrict__ agg, float* __restrict__ h,
                        const float* __restrict__ Wkn, const float* __restrict__ bk,
                        const float* __restrict__ Wks, int li, int n_nodes) {
    int n = blockIdx.x * blockDim.x + threadIdx.x;
    if (n >= n_nodes) return;
    float v = Wkn[li] * agg[n] + bk[li] + Wks[li] * h[n];
    h[n] = fmaxf(v, 0.0f);
    agg[n] = 0.0f;
}

__global__ void node_l3_readout(const float* __restrict__ agg, const float* __restrict__ h,
                                const int* __restrict__ graph_ids,
                                const float* __restrict__ Wkn, const float* __restrict__ bk,
                                const float* __restrict__ Wks, float* __restrict__ hg,
                                int n_nodes) {
    int n = blockIdx.x * blockDim.x + threadIdx.x;
    float val = 0.0f;
    int g = -1;
    if (n < n_nodes) {
        val = fmaxf(Wkn[2] * agg[n] + bk[2] + Wks[2] * h[n], 0.0f);
        g = graph_ids[n];
    }
    int g0 = __shfl(g, 0);
    unsigned long long same = __ballot(g == g0);
    if (same == ~0ULL) {
        for (int o = 32; o > 0; o >>= 1) val += __shfl_down(val, o);
        if ((threadIdx.x & 63) == 0 && g >= 0) atomicAdd(&hg[g], val);
    } else if (g >= 0) {
        atomicAdd(&hg[g], val);
    }
}

// ---------------- launch ----------------

extern "C" void kernel_launch(void* const* d_in, const int* in_sizes, int n_in,
                              void* d_out, int out_size, void* d_ws, size_t ws_size,
                              hipStream_t stream) {
    const float* x        = (const float*)d_in[0];
    const int*   src      = (const int*)d_in[1];
    const int*   dst      = (const int*)d_in[2];
    const int*   graphids = (const int*)d_in[3];
    const float* W0n   = (const float*)d_in[5];
    const float* b0    = (const float*)d_in[6];
    const float* W0s   = (const float*)d_in[7];
    const float* Wkn   = (const float*)d_in[8];
    const float* bk    = (const float*)d_in[9];
    const float* Wks   = (const float*)d_in[10];
    const float* fc1_w = (const float*)d_in[11];
    const float* fc1_b = (const float*)d_in[12];
    const float* out_w = (const float*)d_in[13];
    const float* out_b = (const float*)d_in[14];
    float* out = (float*)d_out;

    const int n_nodes = in_sizes[0] / 8;
    const int n_edges = in_sizes[1];
    const int nbuck   = (n_nodes + BNODE - 1) >> BNODE_LOG;
    const size_t NB   = (size_t)n_nodes * sizeof(float);

    const int node_blocks = (n_nodes + TB - 1) / TB;

    const size_t need = (size_t)n_edges * 4 + 4 * NB +
                        (MAXBUCK + (MAXBUCK + 1) + MAXBUCK + NGRAPHS) * sizeof(int) + 256;

    if (nbuck <= MAXBUCK && n_nodes <= (1 << 20) && ws_size >= need) {
        // ---- fast path ----
        char* ws = (char*)d_ws;
        uint32_t* sorted = (uint32_t*)ws;                 ws += (size_t)n_edges * 4;
        float* xw0 = (float*)ws;                          ws += NB;
        float* s0  = (float*)ws;                          ws += NB;
        float* h_a = (float*)ws;                          ws += NB;
        float* h_b = (float*)ws;                          ws += NB;
        int* counts = (int*)ws;                           ws += MAXBUCK * sizeof(int);
        int* offs   = (int*)ws;                           ws += (MAXBUCK + 1) * sizeof(int);
        int* cursor = (int*)ws;                           ws += MAXBUCK * sizeof(int);
        float* hg   = (float*)ws;

        hipMemsetAsync(counts, 0, nbuck * sizeof(int), stream);
        hipMemsetAsync(hg, 0, NGRAPHS * sizeof(float), stream);

        node_init<<<node_blocks, TB, 0, stream>>>((const float4*)x, W0n, W0s, xw0, s0, n_nodes);
        count_bins<<<2048, TB, 0, stream>>>(dst, n_edges, nbuck, counts);
        scan_offsets<<<1, MAXBUCK, 0, stream>>>(counts, nbuck, offs, cursor);
        place_edges<<<PGRID, TB_P, 0, stream>>>(src, dst, n_edges, nbuck, cursor, sorted);

        layer0_agg<<<nbuck, TB_A, 0, stream>>>(sorted, offs, xw0, s0, b0, h_a, n_nodes);
        layerk_agg<<<nbuck, TB_A, 0, stream>>>(sorted, offs, h_a, Wkn, bk, Wks, 0, h_b, n_nodes);
        layerk_agg<<<nbuck, TB_A, 0, stream>>>(sorted, offs, h_b, Wkn, bk, Wks, 1, h_a, n_nodes);
        layer_last_readout<<<nbuck, TB_A, 0, stream>>>(sorted, offs, h_a, graphids, Wkn, bk, Wks, 2, hg, n_nodes);

        head<<<1, TB, 0, stream>>>(hg, fc1_w, fc1_b, out_w, out_b, out);
    } else {
        // ---- fallback: global-atomic path ----
        char* ws   = (char*)d_ws;
        float* agg = (float*)(ws);
        float* h   = (float*)(ws + NB);
        float* xw0 = (float*)(ws + 2 * NB);
        float* s0  = (float*)(ws + 3 * NB);
        float* hg  = (float*)(ws + 4 * NB);
        const int nquads = n_edges >> 2;
        const int edge_blocks = (nquads + TB - 1) / TB;

        hipMemsetAsync(agg, 0, NB, stream);
        hipMemsetAsync(hg, 0, NGRAPHS * sizeof(float), stream);

        node_init<<<node_blocks, TB, 0, stream>>>((const float4*)x, W0n, W0s, xw0, s0, n_nodes);
        edge_scatter<<<edge_blocks, TB, 0, stream>>>((const int4*)src, (const int4*)dst, xw0, agg, nquads);
        node_l0<<<node_blocks, TB, 0, stream>>>(agg, s0, b0, h, n_nodes);
        for (int li = 0; li < 2; ++li) {
            edge_scatter<<<edge_blocks, TB, 0, stream>>>((const int4*)src, (const int4*)dst, h, agg, nquads);
            node_lk<<<node_blocks, TB, 0, stream>>>(agg, h, Wkn, bk, Wks, li, n_nodes);
        }
        edge_scatter<<<edge_blocks, TB, 0, stream>>>((const int4*)src, (const int4*)dst, h, agg, nquads);
        node_l3_readout<<<node_blocks, TB, 0, stream>>>(agg, h, graphids, Wkn, bk, Wks, hg, n_nodes);
        head<<<1, TB, 0, stream>>>(hg, fc1_w, fc1_b, out_w, out_b, out);
    }
}